// Round 12
// baseline (208.425 us; speedup 1.0000x reference)
//
#include <hip/hip_runtime.h>
#include <hip/hip_bf16.h>
#include <math.h>

// ---------------------------------------------------------------------------
// GCN forward, algebraically collapsed:
//   h1 = relu( dinv[d]*(sum_{e:dst=d} g[src_e] + g[d]) + b1 ),  g = (x@W1)*dinv
//   pooled = (1/N) * (sum_n w[n]*h1[n]) @ W2 + b2,
//       w[n] = dinv[n]*(wacc[n] + dinv[n]),  wacc[n] = sum_{e:src=n} dinv[dst_e]
//   out = sigmoid(pooled @ Wl + bl)
//
// g stored bf16 (MFMA GEMM). Edges partitioned TWICE into 128-node buckets
// (by dst for aggregation, by src for wacc); records packed 4B.
// agg: one block per 64-row HALF-bucket (grid 2*nbuck), 8 waves/block,
// wave w owns rows with dl&7==w (race-free direct LDS accumulation — NOTE:
// LDS float atomicAdd is a CAS loop, never hot-path it; r10 regression).
// Edges sorted by (half, dst&7, src>>11) so gathers sweep src coherently.
// ---------------------------------------------------------------------------

#define F_IN 256
#define H 64
#define BSHIFT 7
#define BSZ 128
#define NBUCK_MAX 1024
#define P3_CH 8192

typedef __attribute__((ext_vector_type(8))) short bf16x8;
typedef __attribute__((ext_vector_type(4))) float f32x4;

__device__ __forceinline__ ushort f2bf(float f) {
    uint b = __float_as_uint(f);
    return (ushort)((b + 0x7FFFu + ((b >> 16) & 1u)) >> 16);   // RNE
}
__device__ __forceinline__ float bf2f(ushort u) {
    return __uint_as_float(((uint)u) << 16);
}

// ---- P1: dual bucket histogram (dst>>7 and src>>7) -------------------------
__global__ __launch_bounds__(256) void hist_kernel(const int* __restrict__ ei,
                                                   int* __restrict__ bcnt_d,
                                                   int* __restrict__ bcnt_s,
                                                   int E, int nbuck) {
    __shared__ int hd[NBUCK_MAX], hs[NBUCK_MAX];
    for (int i = threadIdx.x; i < NBUCK_MAX; i += 256) { hd[i] = 0; hs[i] = 0; }
    __syncthreads();
    int stride = gridDim.x * 256;
    for (int e = blockIdx.x * 256 + threadIdx.x; e < E; e += stride) {
        atomicAdd(&hd[ei[E + e] >> BSHIFT], 1);
        atomicAdd(&hs[ei[e] >> BSHIFT], 1);
    }
    __syncthreads();
    for (int b = threadIdx.x; b < nbuck; b += 256) {
        if (hd[b]) atomicAdd(&bcnt_d[b], hd[b]);
        if (hs[b]) atomicAdd(&bcnt_s[b], hs[b]);
    }
}

// ---- P2: scan bucket counts (block 0: dst, block 1: src) -------------------
__global__ __launch_bounds__(1024) void bscan_kernel(const int* __restrict__ bcnt_d,
                                                     const int* __restrict__ bcnt_s,
                                                     int* __restrict__ bbase_d,
                                                     int* __restrict__ bcur_d,
                                                     int* __restrict__ bbase_s,
                                                     int* __restrict__ bcur_s,
                                                     int nbuck, int E) {
    __shared__ int lds[1024];
    int t = threadIdx.x;
    const int* bcnt = blockIdx.x ? bcnt_s : bcnt_d;
    int* bbase = blockIdx.x ? bbase_s : bbase_d;
    int* bcur  = blockIdx.x ? bcur_s  : bcur_d;
    int v = (t < nbuck) ? bcnt[t] : 0;
    lds[t] = v;
    __syncthreads();
    #pragma unroll
    for (int off = 1; off < 1024; off <<= 1) {
        int u = (t >= off) ? lds[t - off] : 0;
        __syncthreads();
        lds[t] += u;
        __syncthreads();
    }
    if (t < nbuck) { bbase[t] = lds[t] - v; bcur[t] = lds[t] - v; }
    if (t == 0) bbase[nbuck] = E;
}

// ---- P3: partition edges into bucket regions (packed 4B records) -----------
__global__ __launch_bounds__(512) void part_kernel(const int* __restrict__ ei,
                                                   int* __restrict__ bcur,
                                                   int* __restrict__ recs,
                                                   int E, int keyIsDst) {
    __shared__ int hist[NBUCK_MAX], segb[NBUCK_MAX], blkb[NBUCK_MAX], ctr[NBUCK_MAX];
    __shared__ int scanbuf[512];
    __shared__ int stage[P3_CH];
    __shared__ ushort sbuck[P3_CH];
    int t = threadIdx.x;
    int base = blockIdx.x * P3_CH;
    int cnt = E - base; if (cnt > P3_CH) cnt = P3_CH;
    for (int i = t; i < NBUCK_MAX; i += 512) { hist[i] = 0; ctr[i] = 0; }
    __syncthreads();
    for (int i = t; i < cnt; i += 512) {
        int key = keyIsDst ? ei[E + base + i] : ei[base + i];
        atomicAdd(&hist[key >> BSHIFT], 1);
    }
    __syncthreads();
    int v0 = hist[2 * t], v1 = hist[2 * t + 1];
    int s = v0 + v1;
    scanbuf[t] = s;
    __syncthreads();
    #pragma unroll
    for (int off = 1; off < 512; off <<= 1) {
        int u = (t >= off) ? scanbuf[t - off] : 0;
        __syncthreads();
        scanbuf[t] += u;
        __syncthreads();
    }
    int excl = scanbuf[t] - s;
    segb[2 * t] = excl;
    segb[2 * t + 1] = excl + v0;
    if (v0) blkb[2 * t]     = atomicAdd(&bcur[2 * t],     v0);
    if (v1) blkb[2 * t + 1] = atomicAdd(&bcur[2 * t + 1], v1);
    __syncthreads();
    for (int i = t; i < cnt; i += 512) {
        int sN = ei[base + i], d = ei[E + base + i];
        int key   = keyIsDst ? d : sN;
        int other = keyIsDst ? sN : d;
        int b = key >> BSHIFT;
        int r = atomicAdd(&ctr[b], 1);
        int pos = segb[b] + r;
        stage[pos] = (other << BSHIFT) | (key & (BSZ - 1));
        sbuck[pos] = (ushort)b;
    }
    __syncthreads();
    for (int i = t; i < cnt; i += 512) {
        int b = sbuck[i];
        recs[blkb[b] + (i - segb[b])] = stage[i];
    }
}

// ---- P4: per-dst-bucket counting sort by (half, dst&7, src>>11) + dinv -----
__global__ __launch_bounds__(256) void build_kernel(const int* __restrict__ recs,
                                                    const int* __restrict__ bbase,
                                                    float* __restrict__ dinv,
                                                    int* __restrict__ sedge,
                                                    int* __restrict__ qbase,
                                                    int N, int NSB) {
    __shared__ int cnt[BSZ];
    __shared__ int bh[NBUCK_MAX];
    __shared__ int bbl[NBUCK_MAX];
    __shared__ int bctr[NBUCK_MAX];
    __shared__ int scanbuf[256];
    int b = blockIdx.x, t = threadIdx.x;
    int e0 = bbase[b], e1 = bbase[b + 1];
    if (t < BSZ) cnt[t] = 0;
    for (int i = t; i < NBUCK_MAX; i += 256) { bh[i] = 0; bctr[i] = 0; }
    __syncthreads();
    // seg = (dl>>6)*8 + (dl&7), bin = seg*NSB + (src>>11);  src = p>>7
    for (int i = e0 + t; i < e1; i += 256) {
        int p = recs[i];
        int dl = p & (BSZ - 1);
        atomicAdd(&cnt[dl], 1);
        int seg = (((p >> 6) & 1) << 3) | (p & 7);
        atomicAdd(&bh[seg * NSB + ((unsigned)p >> 18)], 1);
    }
    __syncthreads();
    int b0 = bh[4 * t], b1 = bh[4 * t + 1], b2 = bh[4 * t + 2], b3 = bh[4 * t + 3];
    int s = b0 + b1 + b2 + b3;
    scanbuf[t] = s;
    __syncthreads();
    #pragma unroll
    for (int off = 1; off < 256; off <<= 1) {
        int u = (t >= off) ? scanbuf[t - off] : 0;
        __syncthreads();
        scanbuf[t] += u;
        __syncthreads();
    }
    int excl = scanbuf[t] - s;
    bbl[4 * t] = excl;
    bbl[4 * t + 1] = excl + b0;
    bbl[4 * t + 2] = excl + b0 + b1;
    bbl[4 * t + 3] = excl + b0 + b1 + b2;
    __syncthreads();
    if (t < 16) qbase[b * 16 + t] = bbl[t * NSB];
    if (t < BSZ) {
        int n = (b << BSHIFT) + t;
        if (n < N) dinv[n] = rsqrtf(1.0f + (float)cnt[t]);
    }
    __syncthreads();
    for (int i = e0 + t; i < e1; i += 256) {
        int p = recs[i];
        int seg = (((p >> 6) & 1) << 3) | (p & 7);
        int bin = seg * NSB + ((unsigned)p >> 18);
        int pos = atomicAdd(&bctr[bin], 1);
        sedge[e0 + bbl[bin] + pos] = p;
    }
}

// ---- P5: per-src-bucket wacc accumulation (LDS only) -----------------------
__global__ __launch_bounds__(256) void wacc_kernel(const int* __restrict__ srecs,
                                                   const int* __restrict__ bbase_s,
                                                   const float* __restrict__ dinv,
                                                   float* __restrict__ wacc, int N) {
    __shared__ float wl[BSZ];
    int b = blockIdx.x, t = threadIdx.x;
    if (t < BSZ) wl[t] = 0.f;
    __syncthreads();
    int e0 = bbase_s[b], e1 = bbase_s[b + 1];
    for (int i = e0 + t; i < e1; i += 256) {
        int p = srecs[i];
        atomicAdd(&wl[p & (BSZ - 1)], dinv[(unsigned)p >> BSHIFT]);
    }
    __syncthreads();
    int n = (b << BSHIFT) + t;
    if (t < BSZ && n < N) wacc[n] = wl[t];
}

// ---- W1 -> W1^T bf16 (B^T form for MFMA) -----------------------------------
__global__ __launch_bounds__(256) void w1t_kernel(const float* __restrict__ W1,
                                                  ushort* __restrict__ W1t) {
    int idx = blockIdx.x * 256 + threadIdx.x;
    int n = idx >> 8;
    int k = idx & 255;
    W1t[n * 256 + k] = f2bf(W1[k * 64 + n]);
}

// ---- K4: MFMA GEMM  g = (x @ W1) * dinv  (bf16 out) ------------------------
__global__ __launch_bounds__(256) void gemm_mfma(const float* __restrict__ x,
                                                 const ushort* __restrict__ W1t,
                                                 const float* __restrict__ dinv,
                                                 ushort* __restrict__ gb, int M) {
    __shared__ ushort As[64 * 256];   // 32 KB, row-major [m][k], swizzled
    __shared__ ushort Bs[64 * 256];   // 32 KB, row-major [n][k], swizzled
    int t = threadIdx.x;
    int rowbase = blockIdx.x * 64;

    #pragma unroll
    for (int i = 0; i < 8; ++i) {
        int idx = t + i * 256;
        int r   = idx >> 5;
        int c8  = idx & 31;
        int row = rowbase + r;
        float4 v0 = make_float4(0.f, 0.f, 0.f, 0.f);
        float4 v1 = v0;
        if (row < M) {
            const float* xp = &x[(size_t)row * F_IN + c8 * 8];
            v0 = *reinterpret_cast<const float4*>(xp);
            v1 = *reinterpret_cast<const float4*>(xp + 4);
        }
        ushort h[8] = { f2bf(v0.x), f2bf(v0.y), f2bf(v0.z), f2bf(v0.w),
                        f2bf(v1.x), f2bf(v1.y), f2bf(v1.z), f2bf(v1.w) };
        int byteoff = r * 512 + ((c8 * 16) ^ ((r & 15) << 4));
        *reinterpret_cast<uint4*>((char*)As + byteoff) = *reinterpret_cast<uint4*>(h);
    }
    #pragma unroll
    for (int i = 0; i < 8; ++i) {
        int idx = t + i * 256;
        int r   = idx >> 5;
        int c8  = idx & 31;
        uint4 v = *reinterpret_cast<const uint4*>(&W1t[r * 256 + c8 * 8]);
        int byteoff = r * 512 + ((c8 * 16) ^ ((r & 15) << 4));
        *reinterpret_cast<uint4*>((char*)Bs + byteoff) = v;
    }
    __syncthreads();

    int lane = t & 63;
    int w    = t >> 6;
    int lsw  = (lane & 15) << 4;
    f32x4 acc0 = {0.f, 0.f, 0.f, 0.f}, acc1 = acc0, acc2 = acc0, acc3 = acc0;
    int ra = w * 16 + (lane & 15);
    #pragma unroll
    for (int c = 0; c < 8; ++c) {
        int kb = c * 64 + ((lane >> 4) << 4);
        int kbs = kb ^ lsw;
        bf16x8 a = *reinterpret_cast<const bf16x8*>((char*)As + ra * 512 + kbs);
        bf16x8 bf0 = *reinterpret_cast<const bf16x8*>((char*)Bs + ( 0 + (lane & 15)) * 512 + kbs);
        bf16x8 bf1 = *reinterpret_cast<const bf16x8*>((char*)Bs + (16 + (lane & 15)) * 512 + kbs);
        bf16x8 bf2 = *reinterpret_cast<const bf16x8*>((char*)Bs + (32 + (lane & 15)) * 512 + kbs);
        bf16x8 bf3 = *reinterpret_cast<const bf16x8*>((char*)Bs + (48 + (lane & 15)) * 512 + kbs);
        acc0 = __builtin_amdgcn_mfma_f32_16x16x32_bf16(a, bf0, acc0, 0, 0, 0);
        acc1 = __builtin_amdgcn_mfma_f32_16x16x32_bf16(a, bf1, acc1, 0, 0, 0);
        acc2 = __builtin_amdgcn_mfma_f32_16x16x32_bf16(a, bf2, acc2, 0, 0, 0);
        acc3 = __builtin_amdgcn_mfma_f32_16x16x32_bf16(a, bf3, acc3, 0, 0, 0);
    }
    #pragma unroll
    for (int reg = 0; reg < 4; ++reg) {
        int grow = rowbase + w * 16 + ((lane >> 4) << 2) + reg;
        if (grow < M) {
            float dv = dinv[grow];
            ushort* gp = &gb[(size_t)grow * H + (lane & 15)];
            gp[ 0] = f2bf(acc0[reg] * dv);
            gp[16] = f2bf(acc1[reg] * dv);
            gp[32] = f2bf(acc2[reg] * dv);
            gp[48] = f2bf(acc3[reg] * dv);
        }
    }
}

// ---- K6: half-bucket agg (64 rows), 8 waves, wave w owns dl&7==w -----------
__global__ __launch_bounds__(512) void agg_kernel(const ushort* __restrict__ gb,
                                                  const int* __restrict__ bbase,
                                                  const int* __restrict__ qbase,
                                                  const int* __restrict__ sedge,
                                                  const float* __restrict__ dinv,
                                                  const float* __restrict__ wacc,
                                                  const float* __restrict__ b1,
                                                  float* __restrict__ svec, int N) {
    __shared__ float acc[64][H];             // 16 KB
    __shared__ float red[8][64];
    int t = threadIdx.x;
    int lane = t & 63;
    int w = t >> 6;                          // wave 0..7
    int bucket = blockIdx.x >> 1;
    int half   = blockIdx.x & 1;
    float* af = &acc[0][0];
    for (int i = t; i < 64 * H / 4; i += 512)
        reinterpret_cast<float4*>(af)[i] = make_float4(0.f, 0.f, 0.f, 0.f);
    __syncthreads();
    int e0 = bbase[bucket];
    int m  = bbase[bucket + 1] - e0;
    int seg = half * 8 + w;
    int qs = qbase[bucket * 16 + seg];
    int qe = (seg < 15) ? qbase[bucket * 16 + seg + 1] : m;
    const int* sp = sedge + e0;
    int j = qs;
    for (; j + 7 < qe; j += 8) {
        int p0 = sp[j],     p1 = sp[j + 1], p2 = sp[j + 2], p3 = sp[j + 3];
        int p4 = sp[j + 4], p5 = sp[j + 5], p6 = sp[j + 6], p7 = sp[j + 7];
        float g0 = bf2f(gb[(size_t)((unsigned)p0 >> BSHIFT) * H + lane]);
        float g1 = bf2f(gb[(size_t)((unsigned)p1 >> BSHIFT) * H + lane]);
        float g2 = bf2f(gb[(size_t)((unsigned)p2 >> BSHIFT) * H + lane]);
        float g3 = bf2f(gb[(size_t)((unsigned)p3 >> BSHIFT) * H + lane]);
        float g4 = bf2f(gb[(size_t)((unsigned)p4 >> BSHIFT) * H + lane]);
        float g5 = bf2f(gb[(size_t)((unsigned)p5 >> BSHIFT) * H + lane]);
        float g6 = bf2f(gb[(size_t)((unsigned)p6 >> BSHIFT) * H + lane]);
        float g7 = bf2f(gb[(size_t)((unsigned)p7 >> BSHIFT) * H + lane]);
        acc[p0 & 63][lane] += g0;
        acc[p1 & 63][lane] += g1;
        acc[p2 & 63][lane] += g2;
        acc[p3 & 63][lane] += g3;
        acc[p4 & 63][lane] += g4;
        acc[p5 & 63][lane] += g5;
        acc[p6 & 63][lane] += g6;
        acc[p7 & 63][lane] += g7;
    }
    for (; j < qe; ++j) {
        int p = sp[j];
        acc[p & 63][lane] += bf2f(gb[(size_t)((unsigned)p >> BSHIFT) * H + lane]);
    }
    __syncthreads();
    float bb = b1[lane];
    float racc = 0.f;
    #pragma unroll
    for (int r = 0; r < 8; ++r) {
        int dl = r * 8 + w;                  // local row in this half
        int n = (bucket << BSHIFT) + (half << 6) + dl;
        if (n < N) {
            float dv = dinv[n];
            float a = acc[dl][lane] + bf2f(gb[(size_t)n * H + lane]);
            float h1 = fmaxf(dv * a + bb, 0.f);
            racc += (dv * (wacc[n] + dv)) * h1;
        }
    }
    red[w][lane] = racc;
    __syncthreads();
    if (w == 0) {
        float vv = 0.f;
        #pragma unroll
        for (int k = 0; k < 8; ++k) vv += red[k][lane];
        atomicAdd(&svec[lane], vv);
    }
}

// ---- K7: final tiny head ---------------------------------------------------
__global__ void final_kernel(const float* __restrict__ svec,
                             const float* __restrict__ W2, const float* __restrict__ b2,
                             const float* __restrict__ Wl, const float* __restrict__ bl,
                             float* __restrict__ out, float invN) {
    __shared__ float pooled[64];
    __shared__ float sv[64];
    int t = threadIdx.x;
    sv[t] = svec[t];
    __syncthreads();
    float acc = 0.f;
    for (int k = 0; k < 64; ++k) acc += sv[k] * W2[k * 64 + t];
    pooled[t] = acc * invN + b2[t];
    __syncthreads();
    if (t < 10) {
        float a = 0.f;
        for (int j = 0; j < 64; ++j) a += pooled[j] * Wl[j * 10 + t];
        a += bl[t];
        out[t] = 1.f / (1.f + expf(-a));
    }
}

// ---------------------------------------------------------------------------
extern "C" void kernel_launch(void* const* d_in, const int* in_sizes, int n_in,
                              void* d_out, int out_size, void* d_ws, size_t ws_size,
                              hipStream_t stream) {
    const float* x   = (const float*)d_in[0];
    const int*   ei  = (const int*)d_in[1];
    const float* W1  = (const float*)d_in[2];
    const float* b1  = (const float*)d_in[3];
    const float* W2  = (const float*)d_in[4];
    const float* b2  = (const float*)d_in[5];
    const float* Wl  = (const float*)d_in[6];
    const float* bl  = (const float*)d_in[7];
    float* out = (float*)d_out;

    const int N = in_sizes[0] / F_IN;
    const int E = in_sizes[1] / 2;
    const int nbuck = (N + BSZ - 1) >> BSHIFT;       // 782 for N=100000
    const int NSB   = (N + 2047) >> 11;              // 49 src bins (16*NSB <= 1024)

    char* ws = (char*)d_ws;
    size_t off = 0;
    auto carve = [&](size_t bytes) -> char* {
        char* p = ws + off;
        off = (off + bytes + 255) & ~(size_t)255;
        return p;
    };
    int*   bcnt2    = (int*)  carve((size_t)2 * NBUCK_MAX * 4);  // [dst | src]
    int*   bcnt_d   = bcnt2;
    int*   bcnt_s   = bcnt2 + NBUCK_MAX;
    int*   bbase_d  = (int*)  carve((size_t)(NBUCK_MAX + 1) * 4);
    int*   bcur_d   = (int*)  carve((size_t)NBUCK_MAX * 4);
    int*   bbase_s  = (int*)  carve((size_t)(NBUCK_MAX + 1) * 4);
    int*   bcur_s   = (int*)  carve((size_t)NBUCK_MAX * 4);
    int*   qbase    = (int*)  carve((size_t)nbuck * 16 * 4);
    float* dinv     = (float*)carve((size_t)N * 4);
    float* wacc     = (float*)carve((size_t)N * 4);
    float* svec     = (float*)carve(64 * 4);
    ushort* W1t     = (ushort*)carve((size_t)64 * 256 * 2);
    int*   sedge    = (int*)  carve((size_t)E * 4);
    // overlay: [recs_d E*4 | srecs E*4] reused as gb (N*64*2) after wacc
    size_t ovl = (size_t)E * 8;
    size_t gsz = (size_t)N * H * 2;
    char*  ovlp     = carve(ovl > gsz ? ovl : gsz);
    int*   recs_d   = (int*)ovlp;
    int*   srecs    = (int*)(ovlp + (size_t)E * 4);
    ushort* gb      = (ushort*)ovlp;
    (void)ws_size; (void)n_in; (void)out_size;

    hipMemsetAsync(bcnt2, 0, (size_t)2 * NBUCK_MAX * 4, stream);
    hipMemsetAsync(svec, 0, 64 * 4, stream);

    w1t_kernel<<<64, 256, 0, stream>>>(W1, W1t);
    hist_kernel<<<120, 256, 0, stream>>>(ei, bcnt_d, bcnt_s, E, nbuck);
    bscan_kernel<<<2, 1024, 0, stream>>>(bcnt_d, bcnt_s, bbase_d, bcur_d, bbase_s, bcur_s, nbuck, E);
    int gridP3 = (E + P3_CH - 1) / P3_CH;
    part_kernel<<<gridP3, 512, 0, stream>>>(ei, bcur_d, recs_d, E, 1);
    part_kernel<<<gridP3, 512, 0, stream>>>(ei, bcur_s, srecs, E, 0);
    build_kernel<<<nbuck, 256, 0, stream>>>(recs_d, bbase_d, dinv, sedge, qbase, N, NSB);
    wacc_kernel<<<nbuck, 256, 0, stream>>>(srecs, bbase_s, dinv, wacc, N);

    int gridM = (N + 63) / 64;
    gemm_mfma<<<gridM, 256, 0, stream>>>(x, W1t, dinv, gb, N);

    agg_kernel<<<2 * nbuck, 512, 0, stream>>>(gb, bbase_d, qbase, sedge, dinv, wacc, b1, svec, N);

    final_kernel<<<1, 64, 0, stream>>>(svec, W2, b2, Wl, bl, out, 1.0f / (float)N);
}

// Round 13
// 194.287 us; speedup vs baseline: 1.0728x; 1.0728x over previous
//
#include <hip/hip_runtime.h>
#include <hip/hip_bf16.h>
#include <math.h>

// ---------------------------------------------------------------------------
// GCN forward, algebraically collapsed:
//   h1 = relu( dinv[d]*(sum_{e:dst=d} g[src_e] + g[d]) + b1 ),  g = (x@W1)*dinv
//   pooled = (1/N) * (sum_n w[n]*h1[n]) @ W2 + b2,
//       w[n] = dinv[n]*(wacc[n] + dinv[n]),  wacc[n] = sum_{e:src=n} dinv[dst_e]
//   out = sigmoid(pooled @ Wl + bl)
//
// g stored bf16 (MFMA GEMM, A-frags loaded DIRECT from global — no As LDS).
// Edges partitioned TWICE into 128-node buckets (by dst for aggregation, by
// src for wacc); records packed 4B. agg: 8 waves/block, wave w owns dst rows
// with dl&7==w (race-free direct LDS accumulation — NOTE: LDS float atomicAdd
// is a CAS loop, never hot-path it; r10 regression 65->678us). Edges sorted
// (dst&7, src>>10) so gathers sweep src coherently. Half-bucket split (r12)
// regressed: fragmenting the sweep costs more in L2 misses than occupancy wins.
// ---------------------------------------------------------------------------

#define F_IN 256
#define H 64
#define BSHIFT 7
#define BSZ 128
#define NBUCK_MAX 1024
#define P3_CH 8192

typedef __attribute__((ext_vector_type(8))) short bf16x8;
typedef __attribute__((ext_vector_type(4))) float f32x4;

__device__ __forceinline__ ushort f2bf(float f) {
    uint b = __float_as_uint(f);
    return (ushort)((b + 0x7FFFu + ((b >> 16) & 1u)) >> 16);   // RNE
}
__device__ __forceinline__ float bf2f(ushort u) {
    return __uint_as_float(((uint)u) << 16);
}

// ---- P1: dual bucket histogram (dst>>7 and src>>7) -------------------------
__global__ __launch_bounds__(256) void hist_kernel(const int* __restrict__ ei,
                                                   int* __restrict__ bcnt_d,
                                                   int* __restrict__ bcnt_s,
                                                   int E, int nbuck) {
    __shared__ int hd[NBUCK_MAX], hs[NBUCK_MAX];
    for (int i = threadIdx.x; i < NBUCK_MAX; i += 256) { hd[i] = 0; hs[i] = 0; }
    __syncthreads();
    int stride = gridDim.x * 256;
    for (int e = blockIdx.x * 256 + threadIdx.x; e < E; e += stride) {
        atomicAdd(&hd[ei[E + e] >> BSHIFT], 1);
        atomicAdd(&hs[ei[e] >> BSHIFT], 1);
    }
    __syncthreads();
    for (int b = threadIdx.x; b < nbuck; b += 256) {
        if (hd[b]) atomicAdd(&bcnt_d[b], hd[b]);
        if (hs[b]) atomicAdd(&bcnt_s[b], hs[b]);
    }
}

// ---- P2: scan bucket counts (block 0: dst, block 1: src) -------------------
__global__ __launch_bounds__(1024) void bscan_kernel(const int* __restrict__ bcnt_d,
                                                     const int* __restrict__ bcnt_s,
                                                     int* __restrict__ bbase_d,
                                                     int* __restrict__ bcur_d,
                                                     int* __restrict__ bbase_s,
                                                     int* __restrict__ bcur_s,
                                                     int nbuck, int E) {
    __shared__ int lds[1024];
    int t = threadIdx.x;
    const int* bcnt = blockIdx.x ? bcnt_s : bcnt_d;
    int* bbase = blockIdx.x ? bbase_s : bbase_d;
    int* bcur  = blockIdx.x ? bcur_s  : bcur_d;
    int v = (t < nbuck) ? bcnt[t] : 0;
    lds[t] = v;
    __syncthreads();
    #pragma unroll
    for (int off = 1; off < 1024; off <<= 1) {
        int u = (t >= off) ? lds[t - off] : 0;
        __syncthreads();
        lds[t] += u;
        __syncthreads();
    }
    if (t < nbuck) { bbase[t] = lds[t] - v; bcur[t] = lds[t] - v; }
    if (t == 0) bbase[nbuck] = E;
}

// ---- P3: partition edges into bucket regions (packed 4B records) -----------
__global__ __launch_bounds__(512) void part_kernel(const int* __restrict__ ei,
                                                   int* __restrict__ bcur,
                                                   int* __restrict__ recs,
                                                   int E, int keyIsDst) {
    __shared__ int hist[NBUCK_MAX], segb[NBUCK_MAX], blkb[NBUCK_MAX], ctr[NBUCK_MAX];
    __shared__ int scanbuf[512];
    __shared__ int stage[P3_CH];
    __shared__ ushort sbuck[P3_CH];
    int t = threadIdx.x;
    int base = blockIdx.x * P3_CH;
    int cnt = E - base; if (cnt > P3_CH) cnt = P3_CH;
    for (int i = t; i < NBUCK_MAX; i += 512) { hist[i] = 0; ctr[i] = 0; }
    __syncthreads();
    for (int i = t; i < cnt; i += 512) {
        int key = keyIsDst ? ei[E + base + i] : ei[base + i];
        atomicAdd(&hist[key >> BSHIFT], 1);
    }
    __syncthreads();
    int v0 = hist[2 * t], v1 = hist[2 * t + 1];
    int s = v0 + v1;
    scanbuf[t] = s;
    __syncthreads();
    #pragma unroll
    for (int off = 1; off < 512; off <<= 1) {
        int u = (t >= off) ? scanbuf[t - off] : 0;
        __syncthreads();
        scanbuf[t] += u;
        __syncthreads();
    }
    int excl = scanbuf[t] - s;
    segb[2 * t] = excl;
    segb[2 * t + 1] = excl + v0;
    if (v0) blkb[2 * t]     = atomicAdd(&bcur[2 * t],     v0);
    if (v1) blkb[2 * t + 1] = atomicAdd(&bcur[2 * t + 1], v1);
    __syncthreads();
    for (int i = t; i < cnt; i += 512) {
        int sN = ei[base + i], d = ei[E + base + i];
        int key   = keyIsDst ? d : sN;
        int other = keyIsDst ? sN : d;
        int b = key >> BSHIFT;
        int r = atomicAdd(&ctr[b], 1);
        int pos = segb[b] + r;
        stage[pos] = (other << BSHIFT) | (key & (BSZ - 1));
        sbuck[pos] = (ushort)b;
    }
    __syncthreads();
    for (int i = t; i < cnt; i += 512) {
        int b = sbuck[i];
        recs[blkb[b] + (i - segb[b])] = stage[i];
    }
}

// ---- P4: per-dst-bucket counting sort by (dst&7, src>>10) + dinv -----------
__global__ __launch_bounds__(256) void build_kernel(const int* __restrict__ recs,
                                                    const int* __restrict__ bbase,
                                                    float* __restrict__ dinv,
                                                    int* __restrict__ sedge,
                                                    int* __restrict__ qbase,
                                                    int N, int NSB) {
    __shared__ int cnt[BSZ];
    __shared__ int bh[NBUCK_MAX];
    __shared__ int bbl[NBUCK_MAX];
    __shared__ int bctr[NBUCK_MAX];
    __shared__ int scanbuf[256];
    int b = blockIdx.x, t = threadIdx.x;
    int e0 = bbase[b], e1 = bbase[b + 1];
    if (t < BSZ) cnt[t] = 0;
    for (int i = t; i < NBUCK_MAX; i += 256) { bh[i] = 0; bctr[i] = 0; }
    __syncthreads();
    for (int i = e0 + t; i < e1; i += 256) {
        int p = recs[i];
        int dl = p & (BSZ - 1);
        atomicAdd(&cnt[dl], 1);
        atomicAdd(&bh[(p & 7) * NSB + ((unsigned)p >> 17)], 1);  // (dst&7, src>>10)
    }
    __syncthreads();
    int b0 = bh[4 * t], b1 = bh[4 * t + 1], b2 = bh[4 * t + 2], b3 = bh[4 * t + 3];
    int s = b0 + b1 + b2 + b3;
    scanbuf[t] = s;
    __syncthreads();
    #pragma unroll
    for (int off = 1; off < 256; off <<= 1) {
        int u = (t >= off) ? scanbuf[t - off] : 0;
        __syncthreads();
        scanbuf[t] += u;
        __syncthreads();
    }
    int excl = scanbuf[t] - s;
    bbl[4 * t] = excl;
    bbl[4 * t + 1] = excl + b0;
    bbl[4 * t + 2] = excl + b0 + b1;
    bbl[4 * t + 3] = excl + b0 + b1 + b2;
    __syncthreads();
    if (t < 8) qbase[b * 8 + t] = bbl[t * NSB];
    if (t < BSZ) {
        int n = (b << BSHIFT) + t;
        if (n < N) dinv[n] = rsqrtf(1.0f + (float)cnt[t]);
    }
    __syncthreads();
    for (int i = e0 + t; i < e1; i += 256) {
        int p = recs[i];
        int bin = (p & 7) * NSB + ((unsigned)p >> 17);
        int pos = atomicAdd(&bctr[bin], 1);
        sedge[e0 + bbl[bin] + pos] = p;
    }
}

// ---- P5: per-src-bucket wacc accumulation (LDS only) -----------------------
__global__ __launch_bounds__(256) void wacc_kernel(const int* __restrict__ srecs,
                                                   const int* __restrict__ bbase_s,
                                                   const float* __restrict__ dinv,
                                                   float* __restrict__ wacc, int N) {
    __shared__ float wl[BSZ];
    int b = blockIdx.x, t = threadIdx.x;
    if (t < BSZ) wl[t] = 0.f;
    __syncthreads();
    int e0 = bbase_s[b], e1 = bbase_s[b + 1];
    for (int i = e0 + t; i < e1; i += 256) {
        int p = srecs[i];
        atomicAdd(&wl[p & (BSZ - 1)], dinv[(unsigned)p >> BSHIFT]);
    }
    __syncthreads();
    int n = (b << BSHIFT) + t;
    if (t < BSZ && n < N) wacc[n] = wl[t];
}

// ---- W1 -> W1^T bf16 (B^T form for MFMA) -----------------------------------
__global__ __launch_bounds__(256) void w1t_kernel(const float* __restrict__ W1,
                                                  ushort* __restrict__ W1t) {
    int idx = blockIdx.x * 256 + threadIdx.x;
    int n = idx >> 8;
    int k = idx & 255;
    W1t[n * 256 + k] = f2bf(W1[k * 64 + n]);
}

// ---- K4: MFMA GEMM  g = (x @ W1) * dinv  (bf16 out, A direct from global) --
// block: 64 rows, 256 thr (4 waves). Only Bs in LDS (32 KB, XOR-swizzled).
// A-frag loads are fully coalesced: lanes {r,r+16,r+32,r+48} cover 128
// contiguous bytes of x row (rowbase + w*16 + r).
__global__ __launch_bounds__(256) void gemm_mfma(const float* __restrict__ x,
                                                 const ushort* __restrict__ W1t,
                                                 const float* __restrict__ dinv,
                                                 ushort* __restrict__ gb, int M) {
    __shared__ ushort Bs[64 * 256];   // 32 KB, row-major [n][k], swizzled
    int t = threadIdx.x;
    int rowbase = blockIdx.x * 64;

    #pragma unroll
    for (int i = 0; i < 8; ++i) {
        int idx = t + i * 256;
        int r   = idx >> 5;
        int c8  = idx & 31;
        uint4 v = *reinterpret_cast<const uint4*>(&W1t[r * 256 + c8 * 8]);
        int byteoff = r * 512 + ((c8 * 16) ^ ((r & 15) << 4));
        *reinterpret_cast<uint4*>((char*)Bs + byteoff) = v;
    }
    __syncthreads();

    int lane = t & 63;
    int w    = t >> 6;
    int lsw  = (lane & 15) << 4;
    int arow = rowbase + w * 16 + (lane & 15);
    bool avalid = arow < M;
    const float* xp = x + (size_t)arow * F_IN;
    f32x4 acc0 = {0.f, 0.f, 0.f, 0.f}, acc1 = acc0, acc2 = acc0, acc3 = acc0;
    #pragma unroll
    for (int c = 0; c < 8; ++c) {
        int k0 = c * 32 + ((lane >> 4) << 3);      // element offset of 8-f32 chunk
        float4 v0 = make_float4(0.f, 0.f, 0.f, 0.f);
        float4 v1 = v0;
        if (avalid) {
            v0 = *reinterpret_cast<const float4*>(xp + k0);
            v1 = *reinterpret_cast<const float4*>(xp + k0 + 4);
        }
        bf16x8 a;
        a[0] = (short)f2bf(v0.x); a[1] = (short)f2bf(v0.y);
        a[2] = (short)f2bf(v0.z); a[3] = (short)f2bf(v0.w);
        a[4] = (short)f2bf(v1.x); a[5] = (short)f2bf(v1.y);
        a[6] = (short)f2bf(v1.z); a[7] = (short)f2bf(v1.w);
        int kb = c * 64 + ((lane >> 4) << 4);
        int kbs = kb ^ lsw;
        bf16x8 bf0 = *reinterpret_cast<const bf16x8*>((char*)Bs + ( 0 + (lane & 15)) * 512 + kbs);
        bf16x8 bf1 = *reinterpret_cast<const bf16x8*>((char*)Bs + (16 + (lane & 15)) * 512 + kbs);
        bf16x8 bf2 = *reinterpret_cast<const bf16x8*>((char*)Bs + (32 + (lane & 15)) * 512 + kbs);
        bf16x8 bf3 = *reinterpret_cast<const bf16x8*>((char*)Bs + (48 + (lane & 15)) * 512 + kbs);
        acc0 = __builtin_amdgcn_mfma_f32_16x16x32_bf16(a, bf0, acc0, 0, 0, 0);
        acc1 = __builtin_amdgcn_mfma_f32_16x16x32_bf16(a, bf1, acc1, 0, 0, 0);
        acc2 = __builtin_amdgcn_mfma_f32_16x16x32_bf16(a, bf2, acc2, 0, 0, 0);
        acc3 = __builtin_amdgcn_mfma_f32_16x16x32_bf16(a, bf3, acc3, 0, 0, 0);
    }
    #pragma unroll
    for (int reg = 0; reg < 4; ++reg) {
        int grow = rowbase + w * 16 + ((lane >> 4) << 2) + reg;
        if (grow < M) {
            float dv = dinv[grow];
            ushort* gp = &gb[(size_t)grow * H + (lane & 15)];
            gp[ 0] = f2bf(acc0[reg] * dv);
            gp[16] = f2bf(acc1[reg] * dv);
            gp[32] = f2bf(acc2[reg] * dv);
            gp[48] = f2bf(acc3[reg] * dv);
        }
    }
}

// ---- K6: bucket-local LDS accumulation, 8 waves, wave w owns dl&7==w -------
__global__ __launch_bounds__(512) void agg_kernel(const ushort* __restrict__ gb,
                                                  const int* __restrict__ bbase,
                                                  const int* __restrict__ qbase,
                                                  const int* __restrict__ sedge,
                                                  const float* __restrict__ dinv,
                                                  const float* __restrict__ wacc,
                                                  const float* __restrict__ b1,
                                                  float* __restrict__ svec, int N) {
    __shared__ float acc[BSZ][H];            // 32 KB
    __shared__ float red[8][64];
    int t = threadIdx.x;
    int lane = t & 63;
    int w = t >> 6;                          // wave 0..7
    int b = blockIdx.x;
    float* af = &acc[0][0];
    for (int i = t; i < BSZ * H / 4; i += 512)
        reinterpret_cast<float4*>(af)[i] = make_float4(0.f, 0.f, 0.f, 0.f);
    __syncthreads();
    int e0 = bbase[b];
    int m  = bbase[b + 1] - e0;
    int qs = qbase[b * 8 + w];
    int qe = (w < 7) ? qbase[b * 8 + w + 1] : m;
    const int* sp = sedge + e0;
    int j = qs;
    for (; j + 7 < qe; j += 8) {
        int p0 = sp[j],     p1 = sp[j + 1], p2 = sp[j + 2], p3 = sp[j + 3];
        int p4 = sp[j + 4], p5 = sp[j + 5], p6 = sp[j + 6], p7 = sp[j + 7];
        float g0 = bf2f(gb[(size_t)((unsigned)p0 >> BSHIFT) * H + lane]);
        float g1 = bf2f(gb[(size_t)((unsigned)p1 >> BSHIFT) * H + lane]);
        float g2 = bf2f(gb[(size_t)((unsigned)p2 >> BSHIFT) * H + lane]);
        float g3 = bf2f(gb[(size_t)((unsigned)p3 >> BSHIFT) * H + lane]);
        float g4 = bf2f(gb[(size_t)((unsigned)p4 >> BSHIFT) * H + lane]);
        float g5 = bf2f(gb[(size_t)((unsigned)p5 >> BSHIFT) * H + lane]);
        float g6 = bf2f(gb[(size_t)((unsigned)p6 >> BSHIFT) * H + lane]);
        float g7 = bf2f(gb[(size_t)((unsigned)p7 >> BSHIFT) * H + lane]);
        acc[p0 & (BSZ - 1)][lane] += g0;
        acc[p1 & (BSZ - 1)][lane] += g1;
        acc[p2 & (BSZ - 1)][lane] += g2;
        acc[p3 & (BSZ - 1)][lane] += g3;
        acc[p4 & (BSZ - 1)][lane] += g4;
        acc[p5 & (BSZ - 1)][lane] += g5;
        acc[p6 & (BSZ - 1)][lane] += g6;
        acc[p7 & (BSZ - 1)][lane] += g7;
    }
    for (; j < qe; ++j) {
        int p = sp[j];
        acc[p & (BSZ - 1)][lane] += bf2f(gb[(size_t)((unsigned)p >> BSHIFT) * H + lane]);
    }
    __syncthreads();
    float bb = b1[lane];
    float racc = 0.f;
    #pragma unroll
    for (int r = 0; r < 16; ++r) {
        int dl = r * 8 + w;
        int n = (b << BSHIFT) + dl;
        if (n < N) {
            float dv = dinv[n];
            float a = acc[dl][lane] + bf2f(gb[(size_t)n * H + lane]);
            float h1 = fmaxf(dv * a + bb, 0.f);
            racc += (dv * (wacc[n] + dv)) * h1;
        }
    }
    red[w][lane] = racc;
    __syncthreads();
    if (w == 0) {
        float vv = 0.f;
        #pragma unroll
        for (int k = 0; k < 8; ++k) vv += red[k][lane];
        atomicAdd(&svec[lane], vv);
    }
}

// ---- K7: final tiny head ---------------------------------------------------
__global__ void final_kernel(const float* __restrict__ svec,
                             const float* __restrict__ W2, const float* __restrict__ b2,
                             const float* __restrict__ Wl, const float* __restrict__ bl,
                             float* __restrict__ out, float invN) {
    __shared__ float pooled[64];
    __shared__ float sv[64];
    int t = threadIdx.x;
    sv[t] = svec[t];
    __syncthreads();
    float acc = 0.f;
    for (int k = 0; k < 64; ++k) acc += sv[k] * W2[k * 64 + t];
    pooled[t] = acc * invN + b2[t];
    __syncthreads();
    if (t < 10) {
        float a = 0.f;
        for (int j = 0; j < 64; ++j) a += pooled[j] * Wl[j * 10 + t];
        a += bl[t];
        out[t] = 1.f / (1.f + expf(-a));
    }
}

// ---------------------------------------------------------------------------
extern "C" void kernel_launch(void* const* d_in, const int* in_sizes, int n_in,
                              void* d_out, int out_size, void* d_ws, size_t ws_size,
                              hipStream_t stream) {
    const float* x   = (const float*)d_in[0];
    const int*   ei  = (const int*)d_in[1];
    const float* W1  = (const float*)d_in[2];
    const float* b1  = (const float*)d_in[3];
    const float* W2  = (const float*)d_in[4];
    const float* b2  = (const float*)d_in[5];
    const float* Wl  = (const float*)d_in[6];
    const float* bl  = (const float*)d_in[7];
    float* out = (float*)d_out;

    const int N = in_sizes[0] / F_IN;
    const int E = in_sizes[1] / 2;
    const int nbuck = (N + BSZ - 1) >> BSHIFT;       // 782 for N=100000
    const int NSB   = (N + 1023) >> 10;              // 98 src bins (8*NSB <= 1024)

    char* ws = (char*)d_ws;
    size_t off = 0;
    auto carve = [&](size_t bytes) -> char* {
        char* p = ws + off;
        off = (off + bytes + 255) & ~(size_t)255;
        return p;
    };
    int*   bcnt2    = (int*)  carve((size_t)2 * NBUCK_MAX * 4);  // [dst | src]
    int*   bcnt_d   = bcnt2;
    int*   bcnt_s   = bcnt2 + NBUCK_MAX;
    int*   bbase_d  = (int*)  carve((size_t)(NBUCK_MAX + 1) * 4);
    int*   bcur_d   = (int*)  carve((size_t)NBUCK_MAX * 4);
    int*   bbase_s  = (int*)  carve((size_t)(NBUCK_MAX + 1) * 4);
    int*   bcur_s   = (int*)  carve((size_t)NBUCK_MAX * 4);
    int*   qbase    = (int*)  carve((size_t)nbuck * 8 * 4);
    float* dinv     = (float*)carve((size_t)N * 4);
    float* wacc     = (float*)carve((size_t)N * 4);
    float* svec     = (float*)carve(64 * 4);
    ushort* W1t     = (ushort*)carve((size_t)64 * 256 * 2);
    int*   sedge    = (int*)  carve((size_t)E * 4);
    // overlay: [recs_d E*4 | srecs E*4] reused as gb (N*64*2) after wacc
    size_t ovl = (size_t)E * 8;
    size_t gsz = (size_t)N * H * 2;
    char*  ovlp     = carve(ovl > gsz ? ovl : gsz);
    int*   recs_d   = (int*)ovlp;
    int*   srecs    = (int*)(ovlp + (size_t)E * 4);
    ushort* gb      = (ushort*)ovlp;
    (void)ws_size; (void)n_in; (void)out_size;

    hipMemsetAsync(bcnt2, 0, (size_t)2 * NBUCK_MAX * 4, stream);
    hipMemsetAsync(svec, 0, 64 * 4, stream);

    w1t_kernel<<<64, 256, 0, stream>>>(W1, W1t);
    hist_kernel<<<120, 256, 0, stream>>>(ei, bcnt_d, bcnt_s, E, nbuck);
    bscan_kernel<<<2, 1024, 0, stream>>>(bcnt_d, bcnt_s, bbase_d, bcur_d, bbase_s, bcur_s, nbuck, E);
    int gridP3 = (E + P3_CH - 1) / P3_CH;
    part_kernel<<<gridP3, 512, 0, stream>>>(ei, bcur_d, recs_d, E, 1);
    part_kernel<<<gridP3, 512, 0, stream>>>(ei, bcur_s, srecs, E, 0);
    build_kernel<<<nbuck, 256, 0, stream>>>(recs_d, bbase_d, dinv, sedge, qbase, N, NSB);
    wacc_kernel<<<nbuck, 256, 0, stream>>>(srecs, bbase_s, dinv, wacc, N);

    int gridM = (N + 63) / 64;
    gemm_mfma<<<gridM, 256, 0, stream>>>(x, W1t, dinv, gb, N);

    agg_kernel<<<nbuck, 512, 0, stream>>>(gb, bbase_d, qbase, sedge, dinv, wacc, b1, svec, N);

    final_kernel<<<1, 64, 0, stream>>>(svec, W2, b2, Wl, bl, out, 1.0f / (float)N);
}